// Round 10
// baseline (454.794 us; speedup 1.0000x reference)
//
#include <hip/hip_runtime.h>
#include <hip/hip_bf16.h>
#include <stdint.h>

#define M_DIM 16384   // B*T = 4*4096
#define K_DIM 2048    // H
#define N_DIM 6144    // 3H
#define NT    32      // K-tiles per output tile (K_DIM/64)
#define NTILES 6      // output tiles per persistent block (1536/256)

typedef __attribute__((ext_vector_type(8))) short bf16x8;
typedef __attribute__((ext_vector_type(8))) unsigned short u16x8;
typedef __attribute__((ext_vector_type(4))) float f32x4;

__device__ __forceinline__ unsigned short f2bf(float f) {
  unsigned int u = __float_as_uint(f);
  u += 0x7FFFu + ((u >> 16) & 1u);   // RNE
  return (unsigned short)(u >> 16);
}

__device__ __forceinline__ void load_lds16(const void* g, void* l) {
  __builtin_amdgcn_global_load_lds((const __attribute__((address_space(1))) void*)g,
                                   (__attribute__((address_space(3))) void*)l, 16, 0, 0);
}

#define FENCE asm volatile("" ::: "memory")
#define BAR   do { FENCE; __builtin_amdgcn_s_barrier(); FENCE; } while (0)
#define LGKM0 do { asm volatile("s_waitcnt lgkmcnt(0)" ::: "memory"); \
                   __builtin_amdgcn_sched_barrier(0); } while (0)
#define SGB   __builtin_amdgcn_sched_barrier(0)

// ---------- Pass 1a: hidden fp32 -> bf16 (NT loads: fp32 dead after this) ---
__global__ __launch_bounds__(256) void cvt_hidden(const float* __restrict__ in,
                                                  unsigned short* __restrict__ out) {
  unsigned int base = blockIdx.x * 256u + threadIdx.x;
  #pragma unroll
  for (int i = 0; i < 16; ++i) {
    unsigned int fi = i * 524288u + base;
    f32x4 v = __builtin_nontemporal_load(reinterpret_cast<const f32x4*>(in) + fi);
    ushort4 o;
    o.x = f2bf(v[0]); o.y = f2bf(v[1]); o.z = f2bf(v[2]); o.w = f2bf(v[3]);
    reinterpret_cast<ushort4*>(out)[fi] = o;
  }
}

// ---------- Pass 1b: w_qkv [K][N] fp32 -> Wt [N][K] bf16 ----------
__global__ __launch_bounds__(256) void cvt_w(const float* __restrict__ w,
                                             unsigned short* __restrict__ wt) {
  __shared__ float tile[64][69];
  const int k0 = blockIdx.x * 64;
  const int n0 = blockIdx.y * 64;
  const int t = threadIdx.x;
  #pragma unroll
  for (int i = 0; i < 4; ++i) {
    int idx = i * 256 + t;
    int row = idx >> 4, c4 = idx & 15;
    f32x4 v = __builtin_nontemporal_load(reinterpret_cast<const f32x4*>(
        &w[(size_t)(k0 + row) * N_DIM + n0 + c4 * 4]));
    tile[row][c4 * 4 + 0] = v[0]; tile[row][c4 * 4 + 1] = v[1];
    tile[row][c4 * 4 + 2] = v[2]; tile[row][c4 * 4 + 3] = v[3];
  }
  __syncthreads();
  #pragma unroll
  for (int i = 0; i < 2; ++i) {
    int idx = i * 256 + t;
    int n = idx >> 3, k8 = idx & 7;
    u16x8 v;
    #pragma unroll
    for (int e = 0; e < 8; ++e) v[e] = f2bf(tile[k8 * 8 + e][n]);
    *reinterpret_cast<u16x8*>(&wt[(size_t)(n0 + n) * K_DIM + k0 + k8 * 8]) = v;
  }
}

// ---------- Pass 2: persistent seamless 256x256x64 8-phase bf16 MFMA GEMM ----
// R10 = R8 skeleton + ONE change: b1's 4 ds_reads moved from ph2-top into
//   ph1's MFMA(0,0) shadow (issued after ph1's lgkmcnt, SGB-pinned).
//   SAFETY: b1 reads K(t) data (valid for all waves since prev iter's
//   vmcnt+BAR); retires at this wave's ph2 lgkmcnt, which precedes ph2's exit
//   BAR, which precedes ANY wave's ph3 B{0,1} staging overwrite. The R9 b0
//   shadow (reading ahead of the BAR) was a cross-wave staging race — removed.
// Rest identical to R8: stage spreading ph2 A{0,2} / ph3 B{0,1} /
//   ph4 B{2,3}+A{1,3}; steady vmcnt(6); boundary vmcnt(40); stores through
//   L2 (store-buffer: FIFO vmcnt at t=1 retires them in ~2us vs NT's HBM
//   drain); bias in LDS; swapped-operand MFMA -> f32x4 stores.
__global__ __launch_bounds__(512, 2) void gemm_qkv_8ph(const unsigned short* __restrict__ A,
                                                       const unsigned short* __restrict__ Bt,
                                                       const float* __restrict__ bias,
                                                       float* __restrict__ out) {
  extern __shared__ __align__(16) char smem[];
  const int tid = threadIdx.x, lane = tid & 63, wid = tid >> 6;
  const int wm = wid >> 2, wn = wid & 3;        // 2 x 4 wave grid, 128x64 per wave

  const int xcd = blockIdx.x & 7;
  const int lcl = blockIdx.x >> 3;              // 0..31 within XCD

  const int srow  = tid >> 3;
  const int sslot = (tid & 7) ^ ((tid >> 3) & 7);
  const int r15 = lane & 15, q4 = lane >> 4, x7 = lane & 7;
  const int abase = (wm * 128 + r15) * 128;
  const int bbase = (wn * 64  + r15) * 128;
  const int sw0 = ((0 + q4) ^ x7) * 16;
  const int sw1 = ((4 + q4) ^ x7) * 16;

  // full-tile stage (prologue only): 4 x gload_lds(16B)/thread
  #define STAGE_T(gsrc, ldsbase)                                              \
    { const unsigned short* _g = (gsrc); char* _l = (ldsbase);                \
      load_lds16(_g,                       _l +     wid * 1024);              \
      load_lds16(_g + (size_t)64  * K_DIM, _l + 8192  + wid * 1024);          \
      load_lds16(_g + (size_t)128 * K_DIM, _l + 16384 + wid * 1024);          \
      load_lds16(_g + (size_t)192 * K_DIM, _l + 24576 + wid * 1024); }

  // half-tile stage: chunks cA,cB (each chunk = 64 rows = 8KB)
  #define STAGE_H2(gsrc, ldsbase, cA, cB)                                     \
    { const unsigned short* _g = (gsrc); char* _l = (ldsbase);                \
      load_lds16(_g + (size_t)((cA) * 64) * K_DIM, _l + (cA) * 8192 + wid * 1024); \
      load_lds16(_g + (size_t)((cB) * 64) * K_DIM, _l + (cB) * 8192 + wid * 1024); }

  #define TILE_MAP(jj, m0_, n0_, gA_, gB_)                                    \
    { const int bm_ = xcd * 8 + (lcl >> 2);                                   \
      const int bn_ = (jj) * 4 + (lcl & 3);                                   \
      m0_ = bm_ * 256; n0_ = bn_ * 256;                                       \
      gA_ = A  + (size_t)(m0_ + srow) * K_DIM + sslot * 8;                    \
      gB_ = Bt + (size_t)(n0_ + srow) * K_DIM + sslot * 8; }

  // ---- bias preload into LDS corner (once): 6 tiles x 256 floats ----
  if (tid < 384) {
    const int jj = tid / 64;
    const int o  = (tid & 63) * 4;
    const int bn_ = jj * 4 + (lcl & 3);
    f32x4 bv = *reinterpret_cast<const f32x4*>(&bias[bn_ * 256 + o]);
    *reinterpret_cast<f32x4*>(smem + 131072 + jj * 1024 + o * 4) = bv;
  }
  __builtin_amdgcn_sched_barrier(0);

  // ---- first-tile prologue: K0 + K1 (16 loads), vmcnt(8) => K0 landed ----
  int m0, n0, m0n, n0n;
  const unsigned short *gA, *gB, *gAn, *gBn;
  TILE_MAP(0, m0, n0, gA, gB);
  {
    char* A0 = smem;          char* B0 = smem + 32768;
    char* A1 = smem + 65536;  char* B1 = smem + 98304;
    STAGE_T(gB +  0, B0); STAGE_T(gA +  0, A0);
    STAGE_T(gB + 64, B1); STAGE_T(gA + 64, A1);
    asm volatile("s_waitcnt vmcnt(8)" ::: "memory");
    BAR;
  }

  for (int j = 0; j < NTILES; ++j) {
    const int jn = (j + 1 < NTILES) ? j + 1 : j;
    TILE_MAP(jn, m0n, n0n, gAn, gBn);

    f32x4 acc[2][2][4][2] = {};                        // [qm][qn][mi][ni]
    bf16x8 a[4][2], b0[2][2], b1[2][2];

    for (int t = 0; t < NT; ++t) {
      char* Ab = smem + (t & 1) * 65536;
      char* Bb = Ab + 32768;
      const bool st = (t + 2 < NT) || (j + 1 < NTILES);
      const unsigned short* sA = (t + 2 < NT) ? gA + (size_t)(t + 2) * 64
                                              : gAn + (size_t)(t + 2 - NT) * 64;
      const unsigned short* sB = (t + 2 < NT) ? gB + (size_t)(t + 2) * 64
                                              : gBn + (size_t)(t + 2 - NT) * 64;

      // ---- ph1: read A(qm0)+B(qn0); MFMA quad(0,0); b1 in MFMA shadow ----
      #pragma unroll
      for (int mi = 0; mi < 4; ++mi) {
        const char* p = Ab + abase + mi * (16 * 128);
        a[mi][0] = *(const bf16x8*)(p + sw0);
        a[mi][1] = *(const bf16x8*)(p + sw1);
      }
      #pragma unroll
      for (int ni = 0; ni < 2; ++ni) {
        const char* p = Bb + bbase + ni * (16 * 128);
        b0[ni][0] = *(const bf16x8*)(p + sw0);
        b0[ni][1] = *(const bf16x8*)(p + sw1);
      }
      BAR; LGKM0;
      // b1 shadow-read: regs idle during ph1's MFMA; data (K(t)) valid for all
      // waves; retired by ph2's lgkmcnt before any ph3 staging overwrite.
      #pragma unroll
      for (int ni = 0; ni < 2; ++ni) {
        const char* p = Bb + bbase + (32 + ni * 16) * 128;
        b1[ni][0] = *(const bf16x8*)(p + sw0);
        b1[ni][1] = *(const bf16x8*)(p + sw1);
      }
      SGB;
      __builtin_amdgcn_s_setprio(1);
      #pragma unroll
      for (int mi = 0; mi < 4; ++mi)
        #pragma unroll
        for (int ni = 0; ni < 2; ++ni) {
          acc[0][0][mi][ni] = __builtin_amdgcn_mfma_f32_16x16x32_bf16(b0[ni][0], a[mi][0], acc[0][0][mi][ni], 0, 0, 0);
          acc[0][0][mi][ni] = __builtin_amdgcn_mfma_f32_16x16x32_bf16(b0[ni][1], a[mi][1], acc[0][0][mi][ni], 0, 0, 0);
        }
      __builtin_amdgcn_s_setprio(0);
      BAR;

      // ---- ph2: stage K(t+2).A{0,2}; MFMA quad(0,1) [b1 from shadow] ----
      if (st) STAGE_H2(sA, Ab, 0, 2);
      BAR; LGKM0;
      __builtin_amdgcn_s_setprio(1);
      #pragma unroll
      for (int mi = 0; mi < 4; ++mi)
        #pragma unroll
        for (int ni = 0; ni < 2; ++ni) {
          acc[0][1][mi][ni] = __builtin_amdgcn_mfma_f32_16x16x32_bf16(b1[ni][0], a[mi][0], acc[0][1][mi][ni], 0, 0, 0);
          acc[0][1][mi][ni] = __builtin_amdgcn_mfma_f32_16x16x32_bf16(b1[ni][1], a[mi][1], acc[0][1][mi][ni], 0, 0, 0);
        }
      __builtin_amdgcn_s_setprio(0);
      BAR;

      // ---- ph3: read A(qm1); stage K(t+2).B{0,1}; MFMA quad(1,0) ----
      #pragma unroll
      for (int mi = 0; mi < 4; ++mi) {
        const char* p = Ab + abase + (64 + mi * 16) * 128;
        a[mi][0] = *(const bf16x8*)(p + sw0);
        a[mi][1] = *(const bf16x8*)(p + sw1);
      }
      if (st) STAGE_H2(sB, Bb, 0, 1);
      BAR; LGKM0;
      __builtin_amdgcn_s_setprio(1);
      #pragma unroll
      for (int mi = 0; mi < 4; ++mi)
        #pragma unroll
        for (int ni = 0; ni < 2; ++ni) {
          acc[1][0][mi][ni] = __builtin_amdgcn_mfma_f32_16x16x32_bf16(b0[ni][0], a[mi][0], acc[1][0][mi][ni], 0, 0, 0);
          acc[1][0][mi][ni] = __builtin_amdgcn_mfma_f32_16x16x32_bf16(b0[ni][1], a[mi][1], acc[1][0][mi][ni], 0, 0, 0);
        }
      __builtin_amdgcn_s_setprio(0);
      BAR;

      // ---- ph4: stage K(t+2).B{2,3}+A{1,3}; MFMA quad(1,1); counted vmcnt --
      if (st) { STAGE_H2(sB, Bb, 2, 3); STAGE_H2(sA, Ab, 1, 3); }
      BAR; LGKM0;
      __builtin_amdgcn_s_setprio(1);
      #pragma unroll
      for (int mi = 0; mi < 4; ++mi)
        #pragma unroll
        for (int ni = 0; ni < 2; ++ni) {
          acc[1][1][mi][ni] = __builtin_amdgcn_mfma_f32_16x16x32_bf16(b1[ni][0], a[mi][0], acc[1][1][mi][ni], 0, 0, 0);
          acc[1][1][mi][ni] = __builtin_amdgcn_mfma_f32_16x16x32_bf16(b1[ni][1], a[mi][1], acc[1][1][mi][ni], 0, 0, 0);
        }
      __builtin_amdgcn_s_setprio(0);
      // t==0 (j>0): younger = ST(32)+K(t+2)(8) => vmcnt(40) -> K(t+1) done,
      //   stores in flight. Steady: vmcnt(6). Tail: full drain.
      if (t == 0 && j != 0)  { asm volatile("s_waitcnt vmcnt(40)" ::: "memory"); }
      else if (st)           { asm volatile("s_waitcnt vmcnt(6)"  ::: "memory"); }
      else                   { asm volatile("s_waitcnt vmcnt(0)"  ::: "memory"); }
      BAR;
    }

    // ---- epilogue: bias from LDS + 32 f32x4 stores (through L2) ----
    const char* bl = smem + 131072 + j * 1024;
    f32x4 bq[2][2];
    #pragma unroll
    for (int qn = 0; qn < 2; ++qn)
      #pragma unroll
      for (int ni = 0; ni < 2; ++ni)
        bq[qn][ni] = *reinterpret_cast<const f32x4*>(
            bl + (wn * 64 + qn * 32 + ni * 16 + q4 * 4) * 4);

    #pragma unroll
    for (int qm = 0; qm < 2; ++qm)
      #pragma unroll
      for (int mi = 0; mi < 4; ++mi) {
        const int m = m0 + wm * 128 + qm * 64 + mi * 16 + r15;
        const int bb_ = m >> 12, tt = m & 4095;
        float* orow = out + (size_t)bb_ * 8388608 + (size_t)tt * 128;
        #pragma unroll
        for (int qn = 0; qn < 2; ++qn)
          #pragma unroll
          for (int ni = 0; ni < 2; ++ni) {
            const int col = n0 + wn * 64 + qn * 32 + ni * 16 + q4 * 4;
            const int which = col >> 11, head = (col & 2047) >> 7, hd = col & 127;
            f32x4 v = acc[qm][qn][mi][ni] + bq[qn][ni];
            *reinterpret_cast<f32x4*>(orow + (size_t)which * 33554432 +
                                      (size_t)head * 524288 + hd) = v;
          }
      }

    m0 = m0n; n0 = n0n; gA = gAn; gB = gBn;   // advance to next tile
  }
  #undef STAGE_T
  #undef STAGE_H2
  #undef TILE_MAP
}

// ---------- Fallback: naive fp32 ----------
__global__ __launch_bounds__(256) void naive_qkv(const float* __restrict__ h,
                                                 const float* __restrict__ w,
                                                 const float* __restrict__ bias,
                                                 float* __restrict__ out) {
  const int m = blockIdx.x;
  const int n = blockIdx.y * 256 + threadIdx.x;
  const float* hr = h + (size_t)m * K_DIM;
  float acc = bias[n];
  for (int k = 0; k < K_DIM; ++k) acc = fmaf(hr[k], w[(size_t)k * N_DIM + n], acc);
  const int which = n >> 11, head = (n & 2047) >> 7, hd = n & 127;
  const int bb = m >> 12, tt = m & 4095;
  out[(size_t)which * 33554432 + (size_t)bb * 8388608 + (size_t)head * 524288 +
      (size_t)tt * 128 + hd] = acc;
}

extern "C" void kernel_launch(void* const* d_in, const int* in_sizes, int n_in,
                              void* d_out, int out_size, void* d_ws, size_t ws_size,
                              hipStream_t stream) {
  const float* hidden = (const float*)d_in[0];
  const float* w_qkv  = (const float*)d_in[1];
  const float* b_qkv  = (const float*)d_in[2];
  float* out = (float*)d_out;

  const size_t needA = (size_t)M_DIM * K_DIM * 2;
  const size_t needB = (size_t)N_DIM * K_DIM * 2;
  if (ws_size >= needA + needB) {
    unsigned short* Abf = (unsigned short*)d_ws;
    unsigned short* Wt  = (unsigned short*)((char*)d_ws + needA);
    (void)hipFuncSetAttribute((const void*)gemm_qkv_8ph,
                              hipFuncAttributeMaxDynamicSharedMemorySize, 137216);
    cvt_hidden<<<2048, 256, 0, stream>>>(hidden, Abf);
    cvt_w<<<dim3(32, 96), 256, 0, stream>>>(w_qkv, Wt);
    gemm_qkv_8ph<<<256, 512, 137216, stream>>>(Abf, Wt, b_qkv, out);
  } else {
    naive_qkv<<<dim3(16384, 24), 256, 0, stream>>>(hidden, w_qkv, b_qkv, out);
  }
}

// Round 11
// 443.033 us; speedup vs baseline: 1.0265x; 1.0265x over previous
//
#include <hip/hip_runtime.h>
#include <hip/hip_bf16.h>
#include <stdint.h>

#define M_DIM 16384   // B*T = 4*4096
#define K_DIM 2048    // H
#define N_DIM 6144    // 3H
#define NT    32      // K-tiles per output tile (K_DIM/64)
#define NTILES 6      // output tiles per persistent block (1536/256)

typedef __attribute__((ext_vector_type(8))) short bf16x8;
typedef __attribute__((ext_vector_type(8))) unsigned short u16x8;
typedef __attribute__((ext_vector_type(4))) float f32x4;

__device__ __forceinline__ unsigned short f2bf(float f) {
  unsigned int u = __float_as_uint(f);
  u += 0x7FFFu + ((u >> 16) & 1u);   // RNE
  return (unsigned short)(u >> 16);
}

__device__ __forceinline__ void load_lds16(const void* g, void* l) {
  __builtin_amdgcn_global_load_lds((const __attribute__((address_space(1))) void*)g,
                                   (__attribute__((address_space(3))) void*)l, 16, 0, 0);
}

#define FENCE asm volatile("" ::: "memory")
#define BAR   do { FENCE; __builtin_amdgcn_s_barrier(); FENCE; } while (0)

// ---------- Pass 1: fused input conversion ----------
// blocks [0,2048): hidden fp32 -> bf16 straight copy (NT loads).
// blocks [2048,5120): w_qkv [K][N] -> Wt [N][K] bf16 transpose via LDS.
__global__ __launch_bounds__(256) void cvt_fused(const float* __restrict__ hidden,
                                                 unsigned short* __restrict__ outh,
                                                 const float* __restrict__ w,
                                                 unsigned short* __restrict__ wt) {
  __shared__ float tile[64][69];
  const int bid = blockIdx.x;
  const int t = threadIdx.x;
  if (bid < 2048) {
    unsigned int base = bid * 256u + t;
    #pragma unroll
    for (int i = 0; i < 16; ++i) {
      unsigned int fi = i * 524288u + base;
      f32x4 v = __builtin_nontemporal_load(reinterpret_cast<const f32x4*>(hidden) + fi);
      ushort4 o;
      o.x = f2bf(v[0]); o.y = f2bf(v[1]); o.z = f2bf(v[2]); o.w = f2bf(v[3]);
      reinterpret_cast<ushort4*>(outh)[fi] = o;
    }
  } else {
    const int wb = bid - 2048;                  // 0..3071
    const int k0 = (wb / 96) * 64;              // 32 k-tiles
    const int n0 = (wb % 96) * 64;              // 96 n-tiles
    #pragma unroll
    for (int i = 0; i < 4; ++i) {
      int idx = i * 256 + t;
      int row = idx >> 4, c4 = idx & 15;
      f32x4 v = __builtin_nontemporal_load(reinterpret_cast<const f32x4*>(
          &w[(size_t)(k0 + row) * N_DIM + n0 + c4 * 4]));
      tile[row][c4 * 4 + 0] = v[0]; tile[row][c4 * 4 + 1] = v[1];
      tile[row][c4 * 4 + 2] = v[2]; tile[row][c4 * 4 + 3] = v[3];
    }
    __syncthreads();
    #pragma unroll
    for (int i = 0; i < 2; ++i) {
      int idx = i * 256 + t;
      int n = idx >> 3, k8 = idx & 7;
      u16x8 v;
      #pragma unroll
      for (int e = 0; e < 8; ++e) v[e] = f2bf(tile[k8 * 8 + e][n]);
      *reinterpret_cast<u16x8*>(&wt[(size_t)(n0 + n) * K_DIM + k0 + k8 * 8]) = v;
    }
  }
}

// ---------- Pass 2: persistent seamless 256x256x64 8-phase bf16 MFMA GEMM ----
// R11 = R8 skeleton with COMPILER-SCHEDULED intra-phase waits: the manual
//   lgkmcnt(0)+sched_barrier drains forced every wave to retire ALL 12-16
//   LDS reads before its first MFMA; removing them lets hipcc emit
//   fine-grained lgkmcnt(N) per consumer (m97 evidence), overlapping the
//   per-phase LDS storm tail with the MFMA cluster. ds_reads are C++ loads
//   (compiler-tracked register deps — rule 18 applies only to asm ds_reads);
//   raw s_barrier builtin does not force a drain; BAR's memory clobber still
//   orders LDS ops across phases.
// Rest identical to R8: stage spreading ph2 A{0,2} / ph3 B{0,1} /
//   ph4 B{2,3}+A{1,3}; steady vmcnt(6); boundary vmcnt(40); stores through
//   L2; bias in LDS; swapped-operand MFMA -> f32x4 stores.
__global__ __launch_bounds__(512, 2) void gemm_qkv_8ph(const unsigned short* __restrict__ A,
                                                       const unsigned short* __restrict__ Bt,
                                                       const float* __restrict__ bias,
                                                       float* __restrict__ out) {
  extern __shared__ __align__(16) char smem[];
  const int tid = threadIdx.x, lane = tid & 63, wid = tid >> 6;
  const int wm = wid >> 2, wn = wid & 3;        // 2 x 4 wave grid, 128x64 per wave

  const int xcd = blockIdx.x & 7;
  const int lcl = blockIdx.x >> 3;              // 0..31 within XCD

  const int srow  = tid >> 3;
  const int sslot = (tid & 7) ^ ((tid >> 3) & 7);
  const int r15 = lane & 15, q4 = lane >> 4, x7 = lane & 7;
  const int abase = (wm * 128 + r15) * 128;
  const int bbase = (wn * 64  + r15) * 128;
  const int sw0 = ((0 + q4) ^ x7) * 16;
  const int sw1 = ((4 + q4) ^ x7) * 16;

  // full-tile stage (prologue only): 4 x gload_lds(16B)/thread
  #define STAGE_T(gsrc, ldsbase)                                              \
    { const unsigned short* _g = (gsrc); char* _l = (ldsbase);                \
      load_lds16(_g,                       _l +     wid * 1024);              \
      load_lds16(_g + (size_t)64  * K_DIM, _l + 8192  + wid * 1024);          \
      load_lds16(_g + (size_t)128 * K_DIM, _l + 16384 + wid * 1024);          \
      load_lds16(_g + (size_t)192 * K_DIM, _l + 24576 + wid * 1024); }

  // half-tile stage: chunks cA,cB (each chunk = 64 rows = 8KB)
  #define STAGE_H2(gsrc, ldsbase, cA, cB)                                     \
    { const unsigned short* _g = (gsrc); char* _l = (ldsbase);                \
      load_lds16(_g + (size_t)((cA) * 64) * K_DIM, _l + (cA) * 8192 + wid * 1024); \
      load_lds16(_g + (size_t)((cB) * 64) * K_DIM, _l + (cB) * 8192 + wid * 1024); }

  #define TILE_MAP(jj, m0_, n0_, gA_, gB_)                                    \
    { const int bm_ = xcd * 8 + (lcl >> 2);                                   \
      const int bn_ = (jj) * 4 + (lcl & 3);                                   \
      m0_ = bm_ * 256; n0_ = bn_ * 256;                                       \
      gA_ = A  + (size_t)(m0_ + srow) * K_DIM + sslot * 8;                    \
      gB_ = Bt + (size_t)(n0_ + srow) * K_DIM + sslot * 8; }

  // ---- bias preload into LDS corner (once): 6 tiles x 256 floats ----
  if (tid < 384) {
    const int jj = tid / 64;
    const int o  = (tid & 63) * 4;
    const int bn_ = jj * 4 + (lcl & 3);
    f32x4 bv = *reinterpret_cast<const f32x4*>(&bias[bn_ * 256 + o]);
    *reinterpret_cast<f32x4*>(smem + 131072 + jj * 1024 + o * 4) = bv;
  }

  // ---- first-tile prologue: K0 + K1 (16 loads), vmcnt(8) => K0 landed ----
  int m0, n0, m0n, n0n;
  const unsigned short *gA, *gB, *gAn, *gBn;
  TILE_MAP(0, m0, n0, gA, gB);
  {
    char* A0 = smem;          char* B0 = smem + 32768;
    char* A1 = smem + 65536;  char* B1 = smem + 98304;
    STAGE_T(gB +  0, B0); STAGE_T(gA +  0, A0);
    STAGE_T(gB + 64, B1); STAGE_T(gA + 64, A1);
    asm volatile("s_waitcnt vmcnt(8)" ::: "memory");
    BAR;
  }

  for (int j = 0; j < NTILES; ++j) {
    const int jn = (j + 1 < NTILES) ? j + 1 : j;
    TILE_MAP(jn, m0n, n0n, gAn, gBn);

    f32x4 acc[2][2][4][2] = {};                        // [qm][qn][mi][ni]
    bf16x8 a[4][2], b0[2][2], b1[2][2];

    for (int t = 0; t < NT; ++t) {
      char* Ab = smem + (t & 1) * 65536;
      char* Bb = Ab + 32768;
      const bool st = (t + 2 < NT) || (j + 1 < NTILES);
      const unsigned short* sA = (t + 2 < NT) ? gA + (size_t)(t + 2) * 64
                                              : gAn + (size_t)(t + 2 - NT) * 64;
      const unsigned short* sB = (t + 2 < NT) ? gB + (size_t)(t + 2) * 64
                                              : gBn + (size_t)(t + 2 - NT) * 64;

      // ---- ph1: read A(qm0)+B(qn0); MFMA quad(0,0) ----
      #pragma unroll
      for (int mi = 0; mi < 4; ++mi) {
        const char* p = Ab + abase + mi * (16 * 128);
        a[mi][0] = *(const bf16x8*)(p + sw0);
        a[mi][1] = *(const bf16x8*)(p + sw1);
      }
      #pragma unroll
      for (int ni = 0; ni < 2; ++ni) {
        const char* p = Bb + bbase + ni * (16 * 128);
        b0[ni][0] = *(const bf16x8*)(p + sw0);
        b0[ni][1] = *(const bf16x8*)(p + sw1);
      }
      BAR;
      __builtin_amdgcn_s_setprio(1);
      #pragma unroll
      for (int mi = 0; mi < 4; ++mi)
        #pragma unroll
        for (int ni = 0; ni < 2; ++ni) {
          acc[0][0][mi][ni] = __builtin_amdgcn_mfma_f32_16x16x32_bf16(b0[ni][0], a[mi][0], acc[0][0][mi][ni], 0, 0, 0);
          acc[0][0][mi][ni] = __builtin_amdgcn_mfma_f32_16x16x32_bf16(b0[ni][1], a[mi][1], acc[0][0][mi][ni], 0, 0, 0);
        }
      __builtin_amdgcn_s_setprio(0);
      BAR;

      // ---- ph2: read B(qn1); stage K(t+2).A{0,2}; MFMA quad(0,1) ----
      #pragma unroll
      for (int ni = 0; ni < 2; ++ni) {
        const char* p = Bb + bbase + (32 + ni * 16) * 128;
        b1[ni][0] = *(const bf16x8*)(p + sw0);
        b1[ni][1] = *(const bf16x8*)(p + sw1);
      }
      if (st) STAGE_H2(sA, Ab, 0, 2);
      BAR;
      __builtin_amdgcn_s_setprio(1);
      #pragma unroll
      for (int mi = 0; mi < 4; ++mi)
        #pragma unroll
        for (int ni = 0; ni < 2; ++ni) {
          acc[0][1][mi][ni] = __builtin_amdgcn_mfma_f32_16x16x32_bf16(b1[ni][0], a[mi][0], acc[0][1][mi][ni], 0, 0, 0);
          acc[0][1][mi][ni] = __builtin_amdgcn_mfma_f32_16x16x32_bf16(b1[ni][1], a[mi][1], acc[0][1][mi][ni], 0, 0, 0);
        }
      __builtin_amdgcn_s_setprio(0);
      BAR;

      // ---- ph3: read A(qm1); stage K(t+2).B{0,1}; MFMA quad(1,0) ----
      #pragma unroll
      for (int mi = 0; mi < 4; ++mi) {
        const char* p = Ab + abase + (64 + mi * 16) * 128;
        a[mi][0] = *(const bf16x8*)(p + sw0);
        a[mi][1] = *(const bf16x8*)(p + sw1);
      }
      if (st) STAGE_H2(sB, Bb, 0, 1);
      BAR;
      __builtin_amdgcn_s_setprio(1);
      #pragma unroll
      for (int mi = 0; mi < 4; ++mi)
        #pragma unroll
        for (int ni = 0; ni < 2; ++ni) {
          acc[1][0][mi][ni] = __builtin_amdgcn_mfma_f32_16x16x32_bf16(b0[ni][0], a[mi][0], acc[1][0][mi][ni], 0, 0, 0);
          acc[1][0][mi][ni] = __builtin_amdgcn_mfma_f32_16x16x32_bf16(b0[ni][1], a[mi][1], acc[1][0][mi][ni], 0, 0, 0);
        }
      __builtin_amdgcn_s_setprio(0);
      BAR;

      // ---- ph4: stage K(t+2).B{2,3}+A{1,3}; MFMA quad(1,1); counted vmcnt --
      if (st) { STAGE_H2(sB, Bb, 2, 3); STAGE_H2(sA, Ab, 1, 3); }
      BAR;
      __builtin_amdgcn_s_setprio(1);
      #pragma unroll
      for (int mi = 0; mi < 4; ++mi)
        #pragma unroll
        for (int ni = 0; ni < 2; ++ni) {
          acc[1][1][mi][ni] = __builtin_amdgcn_mfma_f32_16x16x32_bf16(b1[ni][0], a[mi][0], acc[1][1][mi][ni], 0, 0, 0);
          acc[1][1][mi][ni] = __builtin_amdgcn_mfma_f32_16x16x32_bf16(b1[ni][1], a[mi][1], acc[1][1][mi][ni], 0, 0, 0);
        }
      __builtin_amdgcn_s_setprio(0);
      // t==0 (j>0): younger = ST(32)+K(t+2)(8) => vmcnt(40) -> K(t+1) done,
      //   stores in flight. Steady: vmcnt(6). Tail: full drain.
      if (t == 0 && j != 0)  { asm volatile("s_waitcnt vmcnt(40)" ::: "memory"); }
      else if (st)           { asm volatile("s_waitcnt vmcnt(6)"  ::: "memory"); }
      else                   { asm volatile("s_waitcnt vmcnt(0)"  ::: "memory"); }
      BAR;
    }

    // ---- epilogue: bias from LDS + 32 f32x4 stores (through L2) ----
    const char* bl = smem + 131072 + j * 1024;
    f32x4 bq[2][2];
    #pragma unroll
    for (int qn = 0; qn < 2; ++qn)
      #pragma unroll
      for (int ni = 0; ni < 2; ++ni)
        bq[qn][ni] = *reinterpret_cast<const f32x4*>(
            bl + (wn * 64 + qn * 32 + ni * 16 + q4 * 4) * 4);

    #pragma unroll
    for (int qm = 0; qm < 2; ++qm)
      #pragma unroll
      for (int mi = 0; mi < 4; ++mi) {
        const int m = m0 + wm * 128 + qm * 64 + mi * 16 + r15;
        const int bb_ = m >> 12, tt = m & 4095;
        float* orow = out + (size_t)bb_ * 8388608 + (size_t)tt * 128;
        #pragma unroll
        for (int qn = 0; qn < 2; ++qn)
          #pragma unroll
          for (int ni = 0; ni < 2; ++ni) {
            const int col = n0 + wn * 64 + qn * 32 + ni * 16 + q4 * 4;
            const int which = col >> 11, head = (col & 2047) >> 7, hd = col & 127;
            f32x4 v = acc[qm][qn][mi][ni] + bq[qn][ni];
            *reinterpret_cast<f32x4*>(orow + (size_t)which * 33554432 +
                                      (size_t)head * 524288 + hd) = v;
          }
      }

    m0 = m0n; n0 = n0n; gA = gAn; gB = gBn;   // advance to next tile
  }
  #undef STAGE_T
  #undef STAGE_H2
  #undef TILE_MAP
}

// ---------- Fallback: naive fp32 ----------
__global__ __launch_bounds__(256) void naive_qkv(const float* __restrict__ h,
                                                 const float* __restrict__ w,
                                                 const float* __restrict__ bias,
                                                 float* __restrict__ out) {
  const int m = blockIdx.x;
  const int n = blockIdx.y * 256 + threadIdx.x;
  const float* hr = h + (size_t)m * K_DIM;
  float acc = bias[n];
  for (int k = 0; k < K_DIM; ++k) acc = fmaf(hr[k], w[(size_t)k * N_DIM + n], acc);
  const int which = n >> 11, head = (n & 2047) >> 7, hd = n & 127;
  const int bb = m >> 12, tt = m & 4095;
  out[(size_t)which * 33554432 + (size_t)bb * 8388608 + (size_t)head * 524288 +
      (size_t)tt * 128 + hd] = acc;
}

extern "C" void kernel_launch(void* const* d_in, const int* in_sizes, int n_in,
                              void* d_out, int out_size, void* d_ws, size_t ws_size,
                              hipStream_t stream) {
  const float* hidden = (const float*)d_in[0];
  const float* w_qkv  = (const float*)d_in[1];
  const float* b_qkv  = (const float*)d_in[2];
  float* out = (float*)d_out;

  const size_t needA = (size_t)M_DIM * K_DIM * 2;
  const size_t needB = (size_t)N_DIM * K_DIM * 2;
  if (ws_size >= needA + needB) {
    unsigned short* Abf = (unsigned short*)d_ws;
    unsigned short* Wt  = (unsigned short*)((char*)d_ws + needA);
    (void)hipFuncSetAttribute((const void*)gemm_qkv_8ph,
                              hipFuncAttributeMaxDynamicSharedMemorySize, 137216);
    cvt_fused<<<5120, 256, 0, stream>>>(hidden, Abf, w_qkv, Wt);
    gemm_qkv_8ph<<<256, 512, 137216, stream>>>(Abf, Wt, b_qkv, out);
  } else {
    naive_qkv<<<dim3(16384, 24), 256, 0, stream>>>(hidden, w_qkv, b_qkv, out);
  }
}